// Round 1
// baseline (1016.371 us; speedup 1.0000x reference)
//
#include <hip/hip_runtime.h>
#include <hip/hip_bf16.h>

// Problem constants (match reference)
#define FIN 256
#define HID 64
#define EMB 2

// ---------------------------------------------------------------------------
// init: region [deg | agg1 | agg2 | sums | cnt] is contiguous in ws.
// deg starts at 1.0 (self-loop), everything after is zeroed.
__global__ void init_kernel(float* __restrict__ p, long n_ones, long n_total) {
    long i = (long)blockIdx.x * blockDim.x + threadIdx.x;
    if (i < n_total) p[i] = (i < n_ones) ? 1.0f : 0.0f;
}

// deg[dst[e]] += 1
__global__ void degree_kernel(const int* __restrict__ dst, float* __restrict__ deg, int E) {
    int i = blockIdx.x * blockDim.x + threadIdx.x;
    if (i < E) atomicAdd(&deg[dst[i]], 1.0f);
}

// deg -> rsqrt(deg)   (deg >= 1 always, so no zero guard needed)
__global__ void dinv_kernel(float* __restrict__ deg, int N) {
    int i = blockIdx.x * blockDim.x + threadIdx.x;
    if (i < N) deg[i] = rsqrtf(deg[i]);
}

// ---------------------------------------------------------------------------
// h1 = x @ W1   (fp32, LDS-tiled)
// Block: 256 threads. thread = (node_local = tid>>4 in [0,16), fg = tid&15, 4 feats).
// W chunk [128][64] in LDS (32 KB), 16 x-rows in LDS (stride 260 -> 4*nl+k banks,
// conflict-free across the 4 node_locals of a wave). Total LDS ~48.6 KB.
__global__ __launch_bounds__(256) void gemm1_kernel(
        const float* __restrict__ x, const float* __restrict__ W,
        float* __restrict__ h1, int N) {
    __shared__ float Wl[128 * HID];     // 32 KB, [k][feat]
    __shared__ float xs[16][260];       // 16.25 KB, padded
    const int tid = threadIdx.x;
    const int nl  = tid >> 4;           // 0..15
    const int fg  = tid & 15;           // 0..15 (4 feats each)

    int per = (N + gridDim.x - 1) / gridDim.x;
    per = (per + 15) & ~15;
    int n0 = blockIdx.x * per;
    int n1 = min(n0 + per, N);

    for (int base = n0; base < n1; base += 16) {
        __syncthreads();  // protect xs against previous iteration's readers
        // stage 16 rows of x (float4 loads)
        for (int i = tid; i < 16 * 64; i += 256) {
            int r = i >> 6, c4 = i & 63;
            int nn = base + r;
            float4 v = make_float4(0.f, 0.f, 0.f, 0.f);
            if (nn < N) v = *(const float4*)&x[(size_t)nn * FIN + c4 * 4];
            *(float4*)&xs[r][c4 * 4] = v;
        }
        float4 acc = make_float4(0.f, 0.f, 0.f, 0.f);
        for (int ch = 0; ch < 2; ++ch) {
            __syncthreads();  // xs staged / previous Wl readers done
            for (int i = tid; i < (128 * 64) / 4; i += 256) {
                *(float4*)&Wl[i * 4] = *(const float4*)&W[ch * 128 * 64 + i * 4];
            }
            __syncthreads();
            #pragma unroll 4
            for (int k = 0; k < 128; ++k) {
                float xv = xs[nl][ch * 128 + k];               // broadcast per 16 lanes
                const float4 w4 = *(const float4*)&Wl[k * 64 + fg * 4];
                acc.x += xv * w4.x; acc.y += xv * w4.y;
                acc.z += xv * w4.z; acc.w += xv * w4.w;
            }
        }
        int node = base + nl;
        if (node < N) *(float4*)&h1[(size_t)node * HID + fg * 4] = acc;
    }
}

// ---------------------------------------------------------------------------
// Layer-1 edge aggregation: one wave per edge (lane = feature).
// agg1[dst] += h1[src] * dinv[src]*dinv[dst]
__global__ void scatter1_kernel(const int* __restrict__ src, const int* __restrict__ dst,
                                const float* __restrict__ dinv, const float* __restrict__ h1,
                                float* __restrict__ agg1, int E) {
    long idx = (long)blockIdx.x * blockDim.x + threadIdx.x;
    if (idx >= (long)E * HID) return;
    int e = (int)(idx >> 6), f = (int)(idx & 63);
    int s = src[e], d = dst[e];
    float norm = dinv[s] * dinv[d];
    atomicAdd(&agg1[(size_t)d * HID + f], h1[(size_t)s * HID + f] * norm);
}

// ---------------------------------------------------------------------------
// Fused: self-loop term + b1 + ReLU + (64->2) GEMM. One wave per node.
__global__ __launch_bounds__(256) void layer2_kernel(
        const float* __restrict__ agg1, const float* __restrict__ h1,
        const float* __restrict__ dinv, const float* __restrict__ b1,
        const float* __restrict__ W2, float* __restrict__ h2, int N) {
    int wave = (int)(((long)blockIdx.x * blockDim.x + threadIdx.x) >> 6);
    int lane = threadIdx.x & 63;
    if (wave >= N) return;
    int n = wave;
    float di = dinv[n];
    float v = agg1[(size_t)n * HID + lane] + h1[(size_t)n * HID + lane] * di * di + b1[lane];
    v = fmaxf(v, 0.0f);
    float r0 = v * W2[lane * EMB + 0];
    float r1 = v * W2[lane * EMB + 1];
    #pragma unroll
    for (int off = 32; off; off >>= 1) {
        r0 += __shfl_down(r0, off);
        r1 += __shfl_down(r1, off);
    }
    if (lane == 0) {
        h2[(size_t)n * EMB + 0] = r0;
        h2[(size_t)n * EMB + 1] = r1;
    }
}

// ---------------------------------------------------------------------------
// Layer-2 edge aggregation (2-dim): one thread per edge.
__global__ void scatter2_kernel(const int* __restrict__ src, const int* __restrict__ dst,
                                const float* __restrict__ dinv, const float* __restrict__ h2,
                                float* __restrict__ agg2, int E) {
    int e = blockIdx.x * blockDim.x + threadIdx.x;
    if (e >= E) return;
    int s = src[e], d = dst[e];
    float norm = dinv[s] * dinv[d];
    atomicAdd(&agg2[(size_t)d * EMB + 0], h2[(size_t)s * EMB + 0] * norm);
    atomicAdd(&agg2[(size_t)d * EMB + 1], h2[(size_t)s * EMB + 1] * norm);
}

// ---------------------------------------------------------------------------
// Pool: add layer-2 self-loop + b2, then segment-sum into graphs.
__global__ void pool_kernel(const float* __restrict__ agg2, const float* __restrict__ h2,
                            const float* __restrict__ dinv, const float* __restrict__ b2,
                            const int* __restrict__ batch,
                            float* __restrict__ sums, float* __restrict__ cnt, int N) {
    int n = blockIdx.x * blockDim.x + threadIdx.x;
    if (n >= N) return;
    float di = dinv[n];
    float di2 = di * di;
    float v0 = agg2[(size_t)n * EMB + 0] + h2[(size_t)n * EMB + 0] * di2 + b2[0];
    float v1 = agg2[(size_t)n * EMB + 1] + h2[(size_t)n * EMB + 1] * di2 + b2[1];
    int g = batch[n];
    atomicAdd(&sums[g * EMB + 0], v0);
    atomicAdd(&sums[g * EMB + 1], v1);
    atomicAdd(&cnt[g], 1.0f);
}

__global__ void final_kernel(const float* __restrict__ sums, const float* __restrict__ cnt,
                             float* __restrict__ out, int G) {
    int g = blockIdx.x * blockDim.x + threadIdx.x;
    if (g >= G) return;
    float c = fmaxf(cnt[g], 1.0f);
    out[g * EMB + 0] = sums[g * EMB + 0] / c;
    out[g * EMB + 1] = sums[g * EMB + 1] / c;
}

// ---------------------------------------------------------------------------
extern "C" void kernel_launch(void* const* d_in, const int* in_sizes, int n_in,
                              void* d_out, int out_size, void* d_ws, size_t ws_size,
                              hipStream_t stream) {
    const float* x    = (const float*)d_in[0];
    const int*   ei   = (const int*)d_in[1];    // [2, E] int32 (harness convention)
    const int*   batch= (const int*)d_in[2];
    const float* W1   = (const float*)d_in[3];
    const float* b1   = (const float*)d_in[4];
    const float* W2   = (const float*)d_in[5];
    const float* b2   = (const float*)d_in[6];
    float* out = (float*)d_out;

    const int N = in_sizes[0] / FIN;        // 100000
    const int E = in_sizes[1] / 2;          // 1600000
    const int G = out_size / EMB;           // 512
    const int* src = ei;
    const int* dst = ei + E;

    // Workspace layout (floats): [deg N | agg1 N*64 | agg2 N*2 | sums G*2 | cnt G | h1 N*64 | h2 N*2]
    float* ws   = (float*)d_ws;
    float* deg  = ws;
    float* agg1 = deg  + N;
    float* agg2 = agg1 + (size_t)N * HID;
    float* sums = agg2 + (size_t)N * EMB;
    float* cnt  = sums + (size_t)G * EMB;
    float* h1   = cnt  + G;
    float* h2   = h1   + (size_t)N * HID;

    const long n_ones  = N;                                      // deg = 1.0
    const long n_init  = (long)N + (long)N * HID + (long)N * EMB // deg+agg1+agg2
                       + (long)G * EMB + (long)G;                // sums+cnt

    // 1. init (deg=1, accumulators=0)
    init_kernel<<<(int)((n_init + 255) / 256), 256, 0, stream>>>(deg, n_ones, n_init);
    // 2. degree + norm
    degree_kernel<<<(E + 255) / 256, 256, 0, stream>>>(dst, deg, E);
    dinv_kernel<<<(N + 255) / 256, 256, 0, stream>>>(deg, N);
    // 3. h1 = x @ W1
    gemm1_kernel<<<400, 256, 0, stream>>>(x, W1, h1, N);
    // 4. layer-1 edge aggregation
    {
        long total = (long)E * HID;
        scatter1_kernel<<<(int)((total + 255) / 256), 256, 0, stream>>>(src, dst, deg, h1, agg1, E);
    }
    // 5. self-loop + b1 + relu + GEMM2
    layer2_kernel<<<(int)(((long)N * 64 + 255) / 256), 256, 0, stream>>>(agg1, h1, deg, b1, W2, h2, N);
    // 6. layer-2 edge aggregation
    scatter2_kernel<<<(E + 255) / 256, 256, 0, stream>>>(src, dst, deg, h2, agg2, E);
    // 7. pool (adds self-loop + b2) and finalize
    pool_kernel<<<(N + 255) / 256, 256, 0, stream>>>(agg2, h2, deg, b2, batch, sums, cnt, N);
    final_kernel<<<(G + 255) / 256, 256, 0, stream>>>(sums, cnt, out, G);
}

// Round 2
// 605.647 us; speedup vs baseline: 1.6782x; 1.6782x over previous
//
#include <hip/hip_runtime.h>
#include <hip/hip_bf16.h>

#define FIN 256
#define HID 64
#define EMB 2

// ---------------------------------------------------------------------------
__global__ void zero_i_kernel(int* __restrict__ p, long n) {
    long i = (long)blockIdx.x * blockDim.x + threadIdx.x;
    if (i < n) p[i] = 0;
}

// in-degree histogram (int atomics)
__global__ void degree_kernel(const int* __restrict__ dst, int* __restrict__ cnt, int E) {
    int i = blockIdx.x * blockDim.x + threadIdx.x;
    if (i < E) atomicAdd(&cnt[dst[i]], 1);
}

// ---------------------------------------------------------------------------
// 3-kernel exclusive scan: rowptr[0]=0, rowptr[i+1]=inclusive(cnt[0..i])
__global__ void scan1_kernel(const int* __restrict__ cnt, int* __restrict__ rowptr,
                             int* __restrict__ bsums, int N) {
    __shared__ int s[256];
    int tid = threadIdx.x;
    int i = blockIdx.x * 256 + tid;
    int v = (i < N) ? cnt[i] : 0;
    s[tid] = v;
    __syncthreads();
    for (int off = 1; off < 256; off <<= 1) {
        int t = (tid >= off) ? s[tid - off] : 0;
        __syncthreads();
        s[tid] += t;
        __syncthreads();
    }
    if (i < N) rowptr[i + 1] = s[tid];
    if (tid == 255) bsums[blockIdx.x] = s[255];
    if (i == 0) rowptr[0] = 0;
}

__global__ void scan2_kernel(int* __restrict__ bsums, int NB) {
    __shared__ int s[512];
    int tid = threadIdx.x;
    s[tid] = (tid < NB) ? bsums[tid] : 0;
    __syncthreads();
    for (int off = 1; off < 512; off <<= 1) {
        int t = (tid >= off) ? s[tid - off] : 0;
        __syncthreads();
        s[tid] += t;
        __syncthreads();
    }
    if (tid < NB) bsums[tid] = s[tid];
}

__global__ void scan3_kernel(int* __restrict__ rowptr, const int* __restrict__ bsums, int N) {
    int i = blockIdx.x * 256 + threadIdx.x;
    if (i < N && blockIdx.x > 0) rowptr[i + 1] += bsums[blockIdx.x - 1];
}

// dinv = rsqrt(indeg + 1)  (self-loop included)
__global__ void dinv_kernel(const int* __restrict__ cnt, float* __restrict__ dinv, int N) {
    int i = blockIdx.x * blockDim.x + threadIdx.x;
    if (i < N) dinv[i] = rsqrtf((float)cnt[i] + 1.0f);
}

// bucket-fill CSR; precompute per-edge norm = dinv[s]*dinv[d]
__global__ void fill_csr_kernel(const int* __restrict__ src, const int* __restrict__ dst,
                                const int* __restrict__ rowptr, int* __restrict__ cursor,
                                const float* __restrict__ dinv,
                                int* __restrict__ csr_src, float* __restrict__ csr_val, int E) {
    int e = blockIdx.x * blockDim.x + threadIdx.x;
    if (e >= E) return;
    int s = src[e], d = dst[e];
    int pos = rowptr[d] + atomicAdd(&cursor[d], 1);
    csr_src[pos] = s;
    csr_val[pos] = dinv[s] * dinv[d];
}

// ---------------------------------------------------------------------------
// h1 = x @ W1 (fp32). Block 256 = 64-node tile; thread = 4 nodes x 4 feats.
// K chunked x128. LDS: xs[64][132] (33 KB) + Wl[128][64] (32 KB) -> 2 blk/CU.
__global__ __launch_bounds__(256) void gemm1_kernel(
        const float* __restrict__ x, const float* __restrict__ W,
        float* __restrict__ h1, int N) {
    __shared__ float xs[64][132];
    __shared__ float Wl[128][64];
    const int tid = threadIdx.x;
    const int fg = tid & 15;   // feat group (4 feats)
    const int ng = tid >> 4;   // node group (4 nodes)
    const int base = blockIdx.x * 64;

    float acc[4][4];
    #pragma unroll
    for (int i = 0; i < 4; ++i)
        #pragma unroll
        for (int j = 0; j < 4; ++j) acc[i][j] = 0.f;

    for (int ch = 0; ch < 2; ++ch) {
        __syncthreads();
        // stage 64 x-rows, 128 k each (coalesced float4; lanes 0..31 contiguous)
        for (int i = tid; i < 64 * 32; i += 256) {
            int r = i >> 5, c4 = i & 31;
            int nn = base + r;
            float4 v = make_float4(0.f, 0.f, 0.f, 0.f);
            if (nn < N) v = *(const float4*)&x[(size_t)nn * FIN + ch * 128 + c4 * 4];
            *(float4*)&xs[r][c4 * 4] = v;
        }
        // stage W chunk [128][64]
        for (int i = tid; i < 128 * 16; i += 256) {
            int r = i >> 4, c4 = i & 15;
            *(float4*)&Wl[r][c4 * 4] = *(const float4*)&W[(size_t)(ch * 128 + r) * HID + c4 * 4];
        }
        __syncthreads();
        #pragma unroll 2
        for (int k = 0; k < 128; ++k) {
            float a0 = xs[ng * 4 + 0][k];
            float a1 = xs[ng * 4 + 1][k];
            float a2 = xs[ng * 4 + 2][k];
            float a3 = xs[ng * 4 + 3][k];
            const float4 w4 = *(const float4*)&Wl[k][fg * 4];
            acc[0][0] += a0 * w4.x; acc[0][1] += a0 * w4.y; acc[0][2] += a0 * w4.z; acc[0][3] += a0 * w4.w;
            acc[1][0] += a1 * w4.x; acc[1][1] += a1 * w4.y; acc[1][2] += a1 * w4.z; acc[1][3] += a1 * w4.w;
            acc[2][0] += a2 * w4.x; acc[2][1] += a2 * w4.y; acc[2][2] += a2 * w4.z; acc[2][3] += a2 * w4.w;
            acc[3][0] += a3 * w4.x; acc[3][1] += a3 * w4.y; acc[3][2] += a3 * w4.z; acc[3][3] += a3 * w4.w;
        }
    }
    #pragma unroll
    for (int i = 0; i < 4; ++i) {
        int nn = base + ng * 4 + i;
        if (nn < N)
            *(float4*)&h1[(size_t)nn * HID + fg * 4] =
                make_float4(acc[i][0], acc[i][1], acc[i][2], acc[i][3]);
    }
}

// ---------------------------------------------------------------------------
// Fused layer-1 aggregation (CSR gather) + self-loop + b1 + ReLU + (64->2).
// One wave per node, lane = feature. No agg1 materialization.
__global__ __launch_bounds__(256) void agg1_layer2_kernel(
        const int* __restrict__ rowptr, const int* __restrict__ csr_src,
        const float* __restrict__ csr_val, const float* __restrict__ h1,
        const float* __restrict__ dinv, const float* __restrict__ b1,
        const float* __restrict__ W2, float* __restrict__ h2, int N) {
    int n = (int)(((long)blockIdx.x * blockDim.x + threadIdx.x) >> 6);
    int f = threadIdx.x & 63;
    if (n >= N) return;
    float di = dinv[n];
    float acc = h1[(size_t)n * HID + f] * (di * di);   // self-loop
    int j0 = rowptr[n], j1 = rowptr[n + 1];
    for (int j = j0; j < j1; ++j) {
        int s = csr_src[j];
        float nm = csr_val[j];
        acc += h1[(size_t)s * HID + f] * nm;
    }
    acc += b1[f];
    acc = fmaxf(acc, 0.f);
    const float2 w2 = *(const float2*)&W2[f * EMB];
    float r0 = acc * w2.x;
    float r1 = acc * w2.y;
    #pragma unroll
    for (int off = 32; off; off >>= 1) {
        r0 += __shfl_down(r0, off);
        r1 += __shfl_down(r1, off);
    }
    if (f == 0) *(float2*)&h2[(size_t)n * EMB] = make_float2(r0, r1);
}

// ---------------------------------------------------------------------------
// Fused layer-2 aggregation + self-loop + b2 + global mean pool (sums/cnt).
// Thread per node; segmented wave scan (batch sorted) -> few atomics.
__global__ __launch_bounds__(256) void agg2_pool_kernel(
        const int* __restrict__ rowptr, const int* __restrict__ csr_src,
        const float* __restrict__ csr_val, const float* __restrict__ h2,
        const float* __restrict__ dinv, const float* __restrict__ b2,
        const int* __restrict__ batch,
        float* __restrict__ sums, float* __restrict__ cntf, int N) {
    int n = blockIdx.x * blockDim.x + threadIdx.x;
    int lane = threadIdx.x & 63;
    float v0 = 0.f, v1 = 0.f, c = 0.f;
    int g = -1;
    if (n < N) {
        float di = dinv[n];
        float di2 = di * di;
        float2 hs = *(const float2*)&h2[(size_t)n * EMB];
        v0 = hs.x * di2;
        v1 = hs.y * di2;
        int j0 = rowptr[n], j1 = rowptr[n + 1];
        for (int j = j0; j < j1; ++j) {
            int s = csr_src[j];
            float nm = csr_val[j];
            float2 hv = *(const float2*)&h2[(size_t)s * EMB];
            v0 += hv.x * nm;
            v1 += hv.y * nm;
        }
        v0 += b2[0];
        v1 += b2[1];
        g = batch[n];
        c = 1.f;
    }
    // segmented inclusive scan over the wave (segments = equal g)
    #pragma unroll
    for (int off = 1; off < 64; off <<= 1) {
        int gg = __shfl_up(g, off);
        float t0 = __shfl_up(v0, off);
        float t1 = __shfl_up(v1, off);
        float tc = __shfl_up(c, off);
        if (lane >= off && gg == g) { v0 += t0; v1 += t1; c += tc; }
    }
    int gn = __shfl_down(g, 1);
    if (g >= 0 && (lane == 63 || gn != g)) {
        atomicAdd(&sums[g * EMB + 0], v0);
        atomicAdd(&sums[g * EMB + 1], v1);
        atomicAdd(&cntf[g], c);
    }
}

__global__ void final_kernel(const float* __restrict__ sums, const float* __restrict__ cntf,
                             float* __restrict__ out, int G) {
    int g = blockIdx.x * blockDim.x + threadIdx.x;
    if (g >= G) return;
    float c = fmaxf(cntf[g], 1.0f);
    out[g * EMB + 0] = sums[g * EMB + 0] / c;
    out[g * EMB + 1] = sums[g * EMB + 1] / c;
}

// ---------------------------------------------------------------------------
extern "C" void kernel_launch(void* const* d_in, const int* in_sizes, int n_in,
                              void* d_out, int out_size, void* d_ws, size_t ws_size,
                              hipStream_t stream) {
    const float* x     = (const float*)d_in[0];
    const int*   ei    = (const int*)d_in[1];
    const int*   batch = (const int*)d_in[2];
    const float* W1    = (const float*)d_in[3];
    const float* b1    = (const float*)d_in[4];
    const float* W2    = (const float*)d_in[5];
    const float* b2    = (const float*)d_in[6];
    float* out = (float*)d_out;

    const int N = in_sizes[0] / FIN;   // 100000
    const int E = in_sizes[1] / 2;     // 1600000
    const int G = out_size / EMB;      // 512
    const int* src = ei;
    const int* dst = ei + E;
    const int NB = (N + 255) / 256;    // scan blocks (<=512)

    // ---- workspace layout ----
    // ints: cnt_i[N] | cursor[N] | rowptr[N+pad] | bsums[512] | csr_src[E]
    // floats: dinv[N] | csr_val[E] | h1[N*64] | h2[N*2] | sums[G*2] | cntf[G]
    int* ip      = (int*)d_ws;
    int* cnt_i   = ip;
    int* cursor  = cnt_i + N;
    int* rowptr  = cursor + N;
    const int rp_sz = (N + 4) & ~3;
    int* bsums   = rowptr + rp_sz;
    int* csr_src = bsums + 512;
    float* fp    = (float*)(csr_src + E);
    float* dinv    = fp;
    float* csr_val = dinv + N;
    float* h1      = csr_val + E;
    float* h2      = h1 + (size_t)N * HID;
    float* sums    = h2 + (size_t)N * EMB;
    float* cntf    = sums + (size_t)G * EMB;

    // 1. zero: cnt_i+cursor (contiguous 2N ints), sums+cntf (3G floats)
    zero_i_kernel<<<(2 * N + 255) / 256, 256, 0, stream>>>(cnt_i, 2L * N);
    zero_i_kernel<<<(3 * G + 255) / 256, 256, 0, stream>>>((int*)sums, 3L * G);
    // 2. degree histogram
    degree_kernel<<<(E + 255) / 256, 256, 0, stream>>>(dst, cnt_i, E);
    // 3. prefix scan -> rowptr
    scan1_kernel<<<NB, 256, 0, stream>>>(cnt_i, rowptr, bsums, N);
    scan2_kernel<<<1, 512, 0, stream>>>(bsums, NB);
    scan3_kernel<<<NB, 256, 0, stream>>>(rowptr, bsums, N);
    // 4. dinv, then CSR fill (with per-edge norm)
    dinv_kernel<<<(N + 255) / 256, 256, 0, stream>>>(cnt_i, dinv, N);
    fill_csr_kernel<<<(E + 255) / 256, 256, 0, stream>>>(src, dst, rowptr, cursor, dinv,
                                                          csr_src, csr_val, E);
    // 5. h1 = x @ W1
    gemm1_kernel<<<(N + 63) / 64, 256, 0, stream>>>(x, W1, h1, N);
    // 6. fused agg1 + relu + W2
    agg1_layer2_kernel<<<(int)(((long)N * 64 + 255) / 256), 256, 0, stream>>>(
        rowptr, csr_src, csr_val, h1, dinv, b1, W2, h2, N);
    // 7. fused agg2 + pool
    agg2_pool_kernel<<<(N + 255) / 256, 256, 0, stream>>>(
        rowptr, csr_src, csr_val, h2, dinv, b2, batch, sums, cntf, N);
    final_kernel<<<(G + 255) / 256, 256, 0, stream>>>(sums, cntf, out, G);
}

// Round 3
// 455.925 us; speedup vs baseline: 2.2293x; 1.3284x over previous
//
#include <hip/hip_runtime.h>
#include <hip/hip_bf16.h>

#define FIN 256
#define HID 64
#define EMB 2

// ---- bf16 helpers (RNE) ----
static __device__ __forceinline__ unsigned short f2bf(float f) {
    union { float f; unsigned int u; } v; v.f = f;
    unsigned int u = v.u;
    unsigned int r = (u + 0x7fffu + ((u >> 16) & 1u)) >> 16;
    return (unsigned short)r;
}
static __device__ __forceinline__ float bf2f(unsigned short h) {
    union { unsigned int u; float f; } v; v.u = ((unsigned int)h) << 16;
    return v.f;
}

// ---------------------------------------------------------------------------
__global__ void zero_i_kernel(int* __restrict__ p, long n) {
    long i = (long)blockIdx.x * blockDim.x + threadIdx.x;
    if (i < n) p[i] = 0;
}

__global__ void degree_kernel(const int* __restrict__ dst, int* __restrict__ cnt, int E) {
    int i = blockIdx.x * blockDim.x + threadIdx.x;
    if (i < E) atomicAdd(&cnt[dst[i]], 1);
}

// 3-kernel exclusive scan: rowptr[0]=0, rowptr[i+1]=inclusive(cnt[0..i])
__global__ void scan1_kernel(const int* __restrict__ cnt, int* __restrict__ rowptr,
                             int* __restrict__ bsums, int N) {
    __shared__ int s[256];
    int tid = threadIdx.x;
    int i = blockIdx.x * 256 + tid;
    int v = (i < N) ? cnt[i] : 0;
    s[tid] = v;
    __syncthreads();
    for (int off = 1; off < 256; off <<= 1) {
        int t = (tid >= off) ? s[tid - off] : 0;
        __syncthreads();
        s[tid] += t;
        __syncthreads();
    }
    if (i < N) rowptr[i + 1] = s[tid];
    if (tid == 255) bsums[blockIdx.x] = s[255];
    if (i == 0) rowptr[0] = 0;
}

__global__ void scan2_kernel(int* __restrict__ bsums, int NB) {
    __shared__ int s[512];
    int tid = threadIdx.x;
    s[tid] = (tid < NB) ? bsums[tid] : 0;
    __syncthreads();
    for (int off = 1; off < 512; off <<= 1) {
        int t = (tid >= off) ? s[tid - off] : 0;
        __syncthreads();
        s[tid] += t;
        __syncthreads();
    }
    if (tid < NB) bsums[tid] = s[tid];
}

__global__ void scan3_kernel(int* __restrict__ rowptr, const int* __restrict__ bsums, int N) {
    int i = blockIdx.x * 256 + threadIdx.x;
    if (i < N && blockIdx.x > 0) rowptr[i + 1] += bsums[blockIdx.x - 1];
}

// dinv = rsqrt(indeg+1); also seed cursor = rowptr for the bucket fill
__global__ void dinv_cursor_kernel(const int* __restrict__ cnt, const int* __restrict__ rowptr,
                                   float* __restrict__ dinv, int* __restrict__ cursor, int N) {
    int i = blockIdx.x * blockDim.x + threadIdx.x;
    if (i < N) {
        dinv[i] = rsqrtf((float)cnt[i] + 1.0f);
        cursor[i] = rowptr[i];
    }
}

// bucket-fill packed CSR entry {src, norm} in one 8 B store
__global__ void fill_csr_kernel(const int* __restrict__ src, const int* __restrict__ dst,
                                int* __restrict__ cursor, const float* __restrict__ dinv,
                                int2* __restrict__ csr, int E) {
    int e = blockIdx.x * blockDim.x + threadIdx.x;
    if (e >= E) return;
    int s = src[e], d = dst[e];
    int pos = atomicAdd(&cursor[d], 1);
    csr[pos] = make_int2(s, __float_as_int(dinv[s] * dinv[d]));
}

// ---------------------------------------------------------------------------
// h1 = x @ W1 (fp32 compute, bf16 store). Block 256 = 64-node tile.
__global__ __launch_bounds__(256) void gemm1_kernel(
        const float* __restrict__ x, const float* __restrict__ W,
        unsigned short* __restrict__ h1b, int N) {
    __shared__ float xs[64][132];
    __shared__ float Wl[128][64];
    const int tid = threadIdx.x;
    const int fg = tid & 15;   // feat group (4 feats)
    const int ng = tid >> 4;   // node group (4 nodes)
    const int base = blockIdx.x * 64;

    float acc[4][4];
    #pragma unroll
    for (int i = 0; i < 4; ++i)
        #pragma unroll
        for (int j = 0; j < 4; ++j) acc[i][j] = 0.f;

    for (int ch = 0; ch < 2; ++ch) {
        __syncthreads();
        for (int i = tid; i < 64 * 32; i += 256) {
            int r = i >> 5, c4 = i & 31;
            int nn = base + r;
            float4 v = make_float4(0.f, 0.f, 0.f, 0.f);
            if (nn < N) v = *(const float4*)&x[(size_t)nn * FIN + ch * 128 + c4 * 4];
            *(float4*)&xs[r][c4 * 4] = v;
        }
        for (int i = tid; i < 128 * 16; i += 256) {
            int r = i >> 4, c4 = i & 15;
            *(float4*)&Wl[r][c4 * 4] = *(const float4*)&W[(size_t)(ch * 128 + r) * HID + c4 * 4];
        }
        __syncthreads();
        #pragma unroll 2
        for (int k = 0; k < 128; ++k) {
            float a0 = xs[ng * 4 + 0][k];
            float a1 = xs[ng * 4 + 1][k];
            float a2 = xs[ng * 4 + 2][k];
            float a3 = xs[ng * 4 + 3][k];
            const float4 w4 = *(const float4*)&Wl[k][fg * 4];
            acc[0][0] += a0 * w4.x; acc[0][1] += a0 * w4.y; acc[0][2] += a0 * w4.z; acc[0][3] += a0 * w4.w;
            acc[1][0] += a1 * w4.x; acc[1][1] += a1 * w4.y; acc[1][2] += a1 * w4.z; acc[1][3] += a1 * w4.w;
            acc[2][0] += a2 * w4.x; acc[2][1] += a2 * w4.y; acc[2][2] += a2 * w4.z; acc[2][3] += a2 * w4.w;
            acc[3][0] += a3 * w4.x; acc[3][1] += a3 * w4.y; acc[3][2] += a3 * w4.z; acc[3][3] += a3 * w4.w;
        }
    }
    ushort4* h14 = (ushort4*)h1b;
    #pragma unroll
    for (int i = 0; i < 4; ++i) {
        int nn = base + ng * 4 + i;
        if (nn < N) {
            ushort4 o;
            o.x = f2bf(acc[i][0]); o.y = f2bf(acc[i][1]);
            o.z = f2bf(acc[i][2]); o.w = f2bf(acc[i][3]);
            h14[(size_t)nn * 16 + fg] = o;
        }
    }
}

// ---------------------------------------------------------------------------
// Fused layer-1 CSR gather + self-loop + b1 + ReLU + (64->2).
// 4 nodes per wave: 16 lanes/node, each lane = 4 feats (ushort4 = 8 B gather).
__global__ __launch_bounds__(256) void agg1_layer2_kernel(
        const int* __restrict__ rowptr, const int2* __restrict__ csr,
        const unsigned short* __restrict__ h1b,
        const float* __restrict__ dinv, const float* __restrict__ b1,
        const float* __restrict__ W2, float* __restrict__ h2, int N) {
    long t = (long)blockIdx.x * blockDim.x + threadIdx.x;
    int n = (int)(t >> 4);
    int li = threadIdx.x & 15;
    if (n >= N) return;
    const ushort4* h14 = (const ushort4*)h1b;

    float di = dinv[n];
    float di2 = di * di;
    ushort4 sl = h14[(size_t)n * 16 + li];
    float v0 = bf2f(sl.x) * di2, v1 = bf2f(sl.y) * di2;
    float v2 = bf2f(sl.z) * di2, v3 = bf2f(sl.w) * di2;

    int j0 = rowptr[n], j1 = rowptr[n + 1];
    int j = j0;
    for (; j + 3 < j1; j += 4) {
        int2 e0 = csr[j], e1 = csr[j + 1], e2 = csr[j + 2], e3 = csr[j + 3];
        ushort4 g0 = h14[(size_t)e0.x * 16 + li];
        ushort4 g1 = h14[(size_t)e1.x * 16 + li];
        ushort4 g2 = h14[(size_t)e2.x * 16 + li];
        ushort4 g3 = h14[(size_t)e3.x * 16 + li];
        float n0 = __int_as_float(e0.y), n1 = __int_as_float(e1.y);
        float n2 = __int_as_float(e2.y), n3 = __int_as_float(e3.y);
        v0 += bf2f(g0.x) * n0 + bf2f(g1.x) * n1 + bf2f(g2.x) * n2 + bf2f(g3.x) * n3;
        v1 += bf2f(g0.y) * n0 + bf2f(g1.y) * n1 + bf2f(g2.y) * n2 + bf2f(g3.y) * n3;
        v2 += bf2f(g0.z) * n0 + bf2f(g1.z) * n1 + bf2f(g2.z) * n2 + bf2f(g3.z) * n3;
        v3 += bf2f(g0.w) * n0 + bf2f(g1.w) * n1 + bf2f(g2.w) * n2 + bf2f(g3.w) * n3;
    }
    for (; j < j1; ++j) {
        int2 e = csr[j];
        ushort4 g = h14[(size_t)e.x * 16 + li];
        float nm = __int_as_float(e.y);
        v0 += bf2f(g.x) * nm; v1 += bf2f(g.y) * nm;
        v2 += bf2f(g.z) * nm; v3 += bf2f(g.w) * nm;
    }

    const float4 b4 = *(const float4*)&b1[li * 4];
    v0 = fmaxf(v0 + b4.x, 0.f); v1 = fmaxf(v1 + b4.y, 0.f);
    v2 = fmaxf(v2 + b4.z, 0.f); v3 = fmaxf(v3 + b4.w, 0.f);

    const float4* W24 = (const float4*)W2;           // W2[64][2] as float4 pairs
    float4 wa = W24[li * 2], wb = W24[li * 2 + 1];
    float r0 = v0 * wa.x + v1 * wa.z + v2 * wb.x + v3 * wb.z;
    float r1 = v0 * wa.y + v1 * wa.w + v2 * wb.y + v3 * wb.w;
    #pragma unroll
    for (int off = 1; off < 16; off <<= 1) {
        r0 += __shfl_xor(r0, off);
        r1 += __shfl_xor(r1, off);
    }
    if (li == 0) *(float2*)&h2[(size_t)n * EMB] = make_float2(r0, r1);
}

// ---------------------------------------------------------------------------
// Fused layer-2 CSR gather + self-loop + b2 + global mean pool.
__global__ __launch_bounds__(256) void agg2_pool_kernel(
        const int* __restrict__ rowptr, const int2* __restrict__ csr,
        const float* __restrict__ h2,
        const float* __restrict__ dinv, const float* __restrict__ b2,
        const int* __restrict__ batch,
        float* __restrict__ sums, float* __restrict__ cntf, int N) {
    int n = blockIdx.x * blockDim.x + threadIdx.x;
    int lane = threadIdx.x & 63;
    const float2* h2v = (const float2*)h2;
    float v0 = 0.f, v1 = 0.f, c = 0.f;
    int g = -1;
    if (n < N) {
        float di = dinv[n];
        float di2 = di * di;
        float2 hs = h2v[n];
        v0 = hs.x * di2;
        v1 = hs.y * di2;
        int j0 = rowptr[n], j1 = rowptr[n + 1];
        int j = j0;
        for (; j + 3 < j1; j += 4) {
            int2 e0 = csr[j], e1 = csr[j + 1], e2 = csr[j + 2], e3 = csr[j + 3];
            float2 a = h2v[e0.x], b = h2v[e1.x], cc = h2v[e2.x], d = h2v[e3.x];
            v0 += a.x * __int_as_float(e0.y) + b.x * __int_as_float(e1.y)
                + cc.x * __int_as_float(e2.y) + d.x * __int_as_float(e3.y);
            v1 += a.y * __int_as_float(e0.y) + b.y * __int_as_float(e1.y)
                + cc.y * __int_as_float(e2.y) + d.y * __int_as_float(e3.y);
        }
        for (; j < j1; ++j) {
            int2 e = csr[j];
            float2 hv = h2v[e.x];
            float nm = __int_as_float(e.y);
            v0 += hv.x * nm;
            v1 += hv.y * nm;
        }
        v0 += b2[0];
        v1 += b2[1];
        g = batch[n];
        c = 1.f;
    }
    #pragma unroll
    for (int off = 1; off < 64; off <<= 1) {
        int gg = __shfl_up(g, off);
        float t0 = __shfl_up(v0, off);
        float t1 = __shfl_up(v1, off);
        float tc = __shfl_up(c, off);
        if (lane >= off && gg == g) { v0 += t0; v1 += t1; c += tc; }
    }
    int gn = __shfl_down(g, 1);
    if (g >= 0 && (lane == 63 || gn != g)) {
        atomicAdd(&sums[g * EMB + 0], v0);
        atomicAdd(&sums[g * EMB + 1], v1);
        atomicAdd(&cntf[g], c);
    }
}

__global__ void final_kernel(const float* __restrict__ sums, const float* __restrict__ cntf,
                             float* __restrict__ out, int G) {
    int g = blockIdx.x * blockDim.x + threadIdx.x;
    if (g >= G) return;
    float c = fmaxf(cntf[g], 1.0f);
    out[g * EMB + 0] = sums[g * EMB + 0] / c;
    out[g * EMB + 1] = sums[g * EMB + 1] / c;
}

// ---------------------------------------------------------------------------
extern "C" void kernel_launch(void* const* d_in, const int* in_sizes, int n_in,
                              void* d_out, int out_size, void* d_ws, size_t ws_size,
                              hipStream_t stream) {
    const float* x     = (const float*)d_in[0];
    const int*   ei    = (const int*)d_in[1];
    const int*   batch = (const int*)d_in[2];
    const float* W1    = (const float*)d_in[3];
    const float* b1    = (const float*)d_in[4];
    const float* W2    = (const float*)d_in[5];
    const float* b2    = (const float*)d_in[6];
    float* out = (float*)d_out;

    const int N = in_sizes[0] / FIN;   // 100000
    const int E = in_sizes[1] / 2;     // 1600000
    const int G = out_size / EMB;      // 512
    const int* src = ei;
    const int* dst = ei + E;
    const int NB = (N + 255) / 256;

    // ---- workspace layout (16 B aligned chunks) ----
    char* p = (char*)d_ws;
    auto take = [&](size_t bytes) { char* r = p; p += (bytes + 15) & ~(size_t)15; return r; };
    int*   cnt_i  = (int*)take(sizeof(int) * N);
    int*   cursor = (int*)take(sizeof(int) * N);
    int*   rowptr = (int*)take(sizeof(int) * (N + 1));
    int*   bsums  = (int*)take(sizeof(int) * 512);
    int2*  csr    = (int2*)take(sizeof(int2) * E);
    unsigned short* h1b = (unsigned short*)take(sizeof(unsigned short) * (size_t)N * HID);
    float* dinv   = (float*)take(sizeof(float) * N);
    float* h2     = (float*)take(sizeof(float) * (size_t)N * EMB);
    float* sums   = (float*)take(sizeof(float) * G * EMB);
    float* cntf   = (float*)take(sizeof(float) * G);

    // 1. zero cnt, sums+cntf (contiguous)
    zero_i_kernel<<<(N + 255) / 256, 256, 0, stream>>>(cnt_i, N);
    zero_i_kernel<<<(3 * G + 255) / 256, 256, 0, stream>>>((int*)sums, 3L * G);
    // 2. degree histogram
    degree_kernel<<<(E + 255) / 256, 256, 0, stream>>>(dst, cnt_i, E);
    // 3. scan -> rowptr
    scan1_kernel<<<NB, 256, 0, stream>>>(cnt_i, rowptr, bsums, N);
    scan2_kernel<<<1, 512, 0, stream>>>(bsums, NB);
    scan3_kernel<<<NB, 256, 0, stream>>>(rowptr, bsums, N);
    // 4. dinv + cursor seed, then packed CSR fill
    dinv_cursor_kernel<<<(N + 255) / 256, 256, 0, stream>>>(cnt_i, rowptr, dinv, cursor, N);
    fill_csr_kernel<<<(E + 255) / 256, 256, 0, stream>>>(src, dst, cursor, dinv, csr, E);
    // 5. h1 = x @ W1 (bf16 out)
    gemm1_kernel<<<(N + 63) / 64, 256, 0, stream>>>(x, W1, h1b, N);
    // 6. fused agg1 + relu + W2 (4 nodes/wave)
    agg1_layer2_kernel<<<(int)(((long)N * 16 + 255) / 256), 256, 0, stream>>>(
        rowptr, csr, h1b, dinv, b1, W2, h2, N);
    // 7. fused agg2 + pool
    agg2_pool_kernel<<<(N + 255) / 256, 256, 0, stream>>>(
        rowptr, csr, h2, dinv, b2, batch, sums, cntf, N);
    final_kernel<<<(G + 255) / 256, 256, 0, stream>>>(sums, cntf, out, G);
}

// Round 4
// 395.887 us; speedup vs baseline: 2.5673x; 1.1517x over previous
//
#include <hip/hip_runtime.h>
#include <hip/hip_bf16.h>

#define FIN 256
#define HID 64
#define EMB 2

typedef __bf16 bf16x8 __attribute__((ext_vector_type(8)));
typedef float  f32x16 __attribute__((ext_vector_type(16)));

// ---- bf16 helpers (RNE) ----
static __device__ __forceinline__ unsigned short f2bf(float f) {
    union { float f; unsigned int u; } v; v.f = f;
    unsigned int u = v.u;
    unsigned int r = (u + 0x7fffu + ((u >> 16) & 1u)) >> 16;
    return (unsigned short)r;
}
static __device__ __forceinline__ float bf2f(unsigned short h) {
    union { unsigned int u; float f; } v; v.u = ((unsigned int)h) << 16;
    return v.f;
}

// ---------------------------------------------------------------------------
__global__ void zero_i_kernel(int* __restrict__ p, long n) {
    long i = (long)blockIdx.x * blockDim.x + threadIdx.x;
    if (i < n) p[i] = 0;
}

__global__ void degree_kernel(const int* __restrict__ dst, int* __restrict__ cnt, int E) {
    int i = blockIdx.x * blockDim.x + threadIdx.x;
    if (i < E) atomicAdd(&cnt[dst[i]], 1);
}

// 3-kernel exclusive scan: rowptr[0]=0, rowptr[i+1]=inclusive(cnt[0..i])
__global__ void scan1_kernel(const int* __restrict__ cnt, int* __restrict__ rowptr,
                             int* __restrict__ bsums, int N) {
    __shared__ int s[256];
    int tid = threadIdx.x;
    int i = blockIdx.x * 256 + tid;
    int v = (i < N) ? cnt[i] : 0;
    s[tid] = v;
    __syncthreads();
    for (int off = 1; off < 256; off <<= 1) {
        int t = (tid >= off) ? s[tid - off] : 0;
        __syncthreads();
        s[tid] += t;
        __syncthreads();
    }
    if (i < N) rowptr[i + 1] = s[tid];
    if (tid == 255) bsums[blockIdx.x] = s[255];
    if (i == 0) rowptr[0] = 0;
}

__global__ void scan2_kernel(int* __restrict__ bsums, int NB) {
    __shared__ int s[512];
    int tid = threadIdx.x;
    s[tid] = (tid < NB) ? bsums[tid] : 0;
    __syncthreads();
    for (int off = 1; off < 512; off <<= 1) {
        int t = (tid >= off) ? s[tid - off] : 0;
        __syncthreads();
        s[tid] += t;
        __syncthreads();
    }
    if (tid < NB) bsums[tid] = s[tid];
}

__global__ void scan3_kernel(int* __restrict__ rowptr, const int* __restrict__ bsums, int N) {
    int i = blockIdx.x * 256 + threadIdx.x;
    if (i < N && blockIdx.x > 0) rowptr[i + 1] += bsums[blockIdx.x - 1];
}

// dinv = rsqrt(indeg+1); also seed cursor = rowptr for the bucket fill
__global__ void dinv_cursor_kernel(const int* __restrict__ cnt, const int* __restrict__ rowptr,
                                   float* __restrict__ dinv, int* __restrict__ cursor, int N) {
    int i = blockIdx.x * blockDim.x + threadIdx.x;
    if (i < N) {
        dinv[i] = rsqrtf((float)cnt[i] + 1.0f);
        cursor[i] = rowptr[i];
    }
}

// bucket-fill packed CSR entry {src, norm} in one 8 B store
__global__ void fill_csr_kernel(const int* __restrict__ src, const int* __restrict__ dst,
                                int* __restrict__ cursor, const float* __restrict__ dinv,
                                int2* __restrict__ csr, int E) {
    int e = blockIdx.x * blockDim.x + threadIdx.x;
    if (e >= E) return;
    int s = src[e], d = dst[e];
    int pos = atomicAdd(&cursor[d], 1);
    csr[pos] = make_int2(s, __float_as_int(dinv[s] * dinv[d]));
}

// ---------------------------------------------------------------------------
// h1 = x @ W1 via MFMA (bf16 hi/lo split: xh*wh + xh*wl + xl*wh, fp32-accurate).
// Block = 64-node x 64-feat tile, 4 waves = four 32x32 quadrants.
// K chunked x64. LDS holds fragment-ordered bf16 hi/lo tiles (32 KB).
__global__ __launch_bounds__(256) void gemm1_kernel(
        const float* __restrict__ x, const float* __restrict__ W,
        unsigned short* __restrict__ h1b, int N) {
    // [region = (grp*4+ks)][lane(64)][j(8)]  (grp = mg for A, ng for B)
    __shared__ __align__(16) __bf16 A_hi[2 * 4 * 64 * 8];
    __shared__ __align__(16) __bf16 A_lo[2 * 4 * 64 * 8];
    __shared__ __align__(16) __bf16 B_hi[2 * 4 * 64 * 8];
    __shared__ __align__(16) __bf16 B_lo[2 * 4 * 64 * 8];

    const int tid = threadIdx.x;
    const int base = blockIdx.x * 64;
    const int w = tid >> 6;           // wave 0..3
    const int l = tid & 63;           // lane
    const int mg = w >> 1, ng = w & 1;

    f32x16 acc = {};

    const int r  = tid & 63;          // staging: A row / B col
    const int ks = tid >> 6;          // staging: k-16-group within chunk
    const int rl = r & 31, rh = r >> 5;

    for (int ch = 0; ch < 4; ++ch) {
        const int ck0 = ch * 64;
        __syncthreads();   // LDS consumers of previous chunk done

        // ---- stage A (x tile): thread = (row r, 16 k at ks*16) ----
        {
            int row = base + r;
            float f[16];
            if (row < N) {
                const float* xp = &x[(size_t)row * FIN + ck0 + ks * 16];
                float4 v0 = *(const float4*)(xp + 0);
                float4 v1 = *(const float4*)(xp + 4);
                float4 v2 = *(const float4*)(xp + 8);
                float4 v3 = *(const float4*)(xp + 12);
                f[0]=v0.x; f[1]=v0.y; f[2]=v0.z; f[3]=v0.w;
                f[4]=v1.x; f[5]=v1.y; f[6]=v1.z; f[7]=v1.w;
                f[8]=v2.x; f[9]=v2.y; f[10]=v2.z; f[11]=v2.w;
                f[12]=v3.x; f[13]=v3.y; f[14]=v3.z; f[15]=v3.w;
            } else {
                #pragma unroll
                for (int q = 0; q < 16; ++q) f[q] = 0.f;
            }
            bf16x8 ha, hb, la, lb;
            #pragma unroll
            for (int q = 0; q < 8; ++q) {
                __bf16 h0 = (__bf16)f[q];
                ha[q] = h0; la[q] = (__bf16)(f[q] - (float)h0);
                __bf16 h1v = (__bf16)f[q + 8];
                hb[q] = h1v; lb[q] = (__bf16)(f[q + 8] - (float)h1v);
            }
            int ra = ((rh * 4 + ks) * 64 + rl) * 8;        // half 0 lanes
            int rb = ((rh * 4 + ks) * 64 + 32 + rl) * 8;   // half 1 lanes
            *(bf16x8*)&A_hi[ra] = ha; *(bf16x8*)&A_hi[rb] = hb;
            *(bf16x8*)&A_lo[ra] = la; *(bf16x8*)&A_lo[rb] = lb;
        }
        // ---- stage B (W tile): thread = (col n=r, 16 k at ks*16) ----
        {
            const float* wp = &W[(size_t)(ck0 + ks * 16) * HID + r];
            float f[16];
            #pragma unroll
            for (int q = 0; q < 16; ++q) f[q] = wp[q * HID];   // coalesced across lanes
            bf16x8 ha, hb, la, lb;
            #pragma unroll
            for (int q = 0; q < 8; ++q) {
                __bf16 h0 = (__bf16)f[q];
                ha[q] = h0; la[q] = (__bf16)(f[q] - (float)h0);
                __bf16 h1v = (__bf16)f[q + 8];
                hb[q] = h1v; lb[q] = (__bf16)(f[q + 8] - (float)h1v);
            }
            int ra = ((rh * 4 + ks) * 64 + rl) * 8;
            int rb = ((rh * 4 + ks) * 64 + 32 + rl) * 8;
            *(bf16x8*)&B_hi[ra] = ha; *(bf16x8*)&B_hi[rb] = hb;
            *(bf16x8*)&B_lo[ra] = la; *(bf16x8*)&B_lo[rb] = lb;
        }
        __syncthreads();

        // ---- compute: 4 k-steps x 3 products ----
        #pragma unroll
        for (int s = 0; s < 4; ++s) {
            bf16x8 a_h = *(const bf16x8*)&A_hi[((mg * 4 + s) * 64 + l) * 8];
            bf16x8 a_l = *(const bf16x8*)&A_lo[((mg * 4 + s) * 64 + l) * 8];
            bf16x8 b_h = *(const bf16x8*)&B_hi[((ng * 4 + s) * 64 + l) * 8];
            bf16x8 b_l = *(const bf16x8*)&B_lo[((ng * 4 + s) * 64 + l) * 8];
            acc = __builtin_amdgcn_mfma_f32_32x32x16_bf16(a_h, b_h, acc, 0, 0, 0);
            acc = __builtin_amdgcn_mfma_f32_32x32x16_bf16(a_h, b_l, acc, 0, 0, 0);
            acc = __builtin_amdgcn_mfma_f32_32x32x16_bf16(a_l, b_h, acc, 0, 0, 0);
        }
    }

    // epilogue: C/D layout col=lane&31, row=(reg&3)+8*(reg>>2)+4*(lane>>5)
    const int col = l & 31;
    const int rbase = 4 * (l >> 5);
    #pragma unroll
    for (int reg = 0; reg < 16; ++reg) {
        int row = (reg & 3) + 8 * (reg >> 2) + rbase;
        int node = base + mg * 32 + row;
        if (node < N) h1b[(size_t)node * HID + ng * 32 + col] = f2bf(acc[reg]);
    }
}

// ---------------------------------------------------------------------------
// Fused layer-1 CSR gather + self-loop + b1 + ReLU + (64->2).
// 4 nodes per wave: 16 lanes/node, each lane = 4 feats (ushort4 = 8 B gather).
__global__ __launch_bounds__(256) void agg1_layer2_kernel(
        const int* __restrict__ rowptr, const int2* __restrict__ csr,
        const unsigned short* __restrict__ h1b,
        const float* __restrict__ dinv, const float* __restrict__ b1,
        const float* __restrict__ W2, float* __restrict__ h2, int N) {
    long t = (long)blockIdx.x * blockDim.x + threadIdx.x;
    int n = (int)(t >> 4);
    int li = threadIdx.x & 15;
    if (n >= N) return;
    const ushort4* h14 = (const ushort4*)h1b;

    float di = dinv[n];
    float di2 = di * di;
    ushort4 sl = h14[(size_t)n * 16 + li];
    float v0 = bf2f(sl.x) * di2, v1 = bf2f(sl.y) * di2;
    float v2 = bf2f(sl.z) * di2, v3 = bf2f(sl.w) * di2;

    int j0 = rowptr[n], j1 = rowptr[n + 1];
    int j = j0;
    for (; j + 3 < j1; j += 4) {
        int2 e0 = csr[j], e1 = csr[j + 1], e2 = csr[j + 2], e3 = csr[j + 3];
        ushort4 g0 = h14[(size_t)e0.x * 16 + li];
        ushort4 g1 = h14[(size_t)e1.x * 16 + li];
        ushort4 g2 = h14[(size_t)e2.x * 16 + li];
        ushort4 g3 = h14[(size_t)e3.x * 16 + li];
        float n0 = __int_as_float(e0.y), n1 = __int_as_float(e1.y);
        float n2 = __int_as_float(e2.y), n3 = __int_as_float(e3.y);
        v0 += bf2f(g0.x) * n0 + bf2f(g1.x) * n1 + bf2f(g2.x) * n2 + bf2f(g3.x) * n3;
        v1 += bf2f(g0.y) * n0 + bf2f(g1.y) * n1 + bf2f(g2.y) * n2 + bf2f(g3.y) * n3;
        v2 += bf2f(g0.z) * n0 + bf2f(g1.z) * n1 + bf2f(g2.z) * n2 + bf2f(g3.z) * n3;
        v3 += bf2f(g0.w) * n0 + bf2f(g1.w) * n1 + bf2f(g2.w) * n2 + bf2f(g3.w) * n3;
    }
    for (; j < j1; ++j) {
        int2 e = csr[j];
        ushort4 g = h14[(size_t)e.x * 16 + li];
        float nm = __int_as_float(e.y);
        v0 += bf2f(g.x) * nm; v1 += bf2f(g.y) * nm;
        v2 += bf2f(g.z) * nm; v3 += bf2f(g.w) * nm;
    }

    const float4 b4 = *(const float4*)&b1[li * 4];
    v0 = fmaxf(v0 + b4.x, 0.f); v1 = fmaxf(v1 + b4.y, 0.f);
    v2 = fmaxf(v2 + b4.z, 0.f); v3 = fmaxf(v3 + b4.w, 0.f);

    const float4* W24 = (const float4*)W2;           // W2[64][2] as float4 pairs
    float4 wa = W24[li * 2], wb = W24[li * 2 + 1];
    float r0 = v0 * wa.x + v1 * wa.z + v2 * wb.x + v3 * wb.z;
    float r1 = v0 * wa.y + v1 * wa.w + v2 * wb.y + v3 * wb.w;
    #pragma unroll
    for (int off = 1; off < 16; off <<= 1) {
        r0 += __shfl_xor(r0, off);
        r1 += __shfl_xor(r1, off);
    }
    if (li == 0) *(float2*)&h2[(size_t)n * EMB] = make_float2(r0, r1);
}

// ---------------------------------------------------------------------------
// Fused layer-2 CSR gather + self-loop + b2 + global mean pool.
__global__ __launch_bounds__(256) void agg2_pool_kernel(
        const int* __restrict__ rowptr, const int2* __restrict__ csr,
        const float* __restrict__ h2,
        const float* __restrict__ dinv, const float* __restrict__ b2,
        const int* __restrict__ batch,
        float* __restrict__ sums, float* __restrict__ cntf, int N) {
    int n = blockIdx.x * blockDim.x + threadIdx.x;
    int lane = threadIdx.x & 63;
    const float2* h2v = (const float2*)h2;
    float v0 = 0.f, v1 = 0.f, c = 0.f;
    int g = -1;
    if (n < N) {
        float di = dinv[n];
        float di2 = di * di;
        float2 hs = h2v[n];
        v0 = hs.x * di2;
        v1 = hs.y * di2;
        int j0 = rowptr[n], j1 = rowptr[n + 1];
        int j = j0;
        for (; j + 3 < j1; j += 4) {
            int2 e0 = csr[j], e1 = csr[j + 1], e2 = csr[j + 2], e3 = csr[j + 3];
            float2 a = h2v[e0.x], b = h2v[e1.x], cc = h2v[e2.x], d = h2v[e3.x];
            v0 += a.x * __int_as_float(e0.y) + b.x * __int_as_float(e1.y)
                + cc.x * __int_as_float(e2.y) + d.x * __int_as_float(e3.y);
            v1 += a.y * __int_as_float(e0.y) + b.y * __int_as_float(e1.y)
                + cc.y * __int_as_float(e2.y) + d.y * __int_as_float(e3.y);
        }
        for (; j < j1; ++j) {
            int2 e = csr[j];
            float2 hv = h2v[e.x];
            float nm = __int_as_float(e.y);
            v0 += hv.x * nm;
            v1 += hv.y * nm;
        }
        v0 += b2[0];
        v1 += b2[1];
        g = batch[n];
        c = 1.f;
    }
    #pragma unroll
    for (int off = 1; off < 64; off <<= 1) {
        int gg = __shfl_up(g, off);
        float t0 = __shfl_up(v0, off);
        float t1 = __shfl_up(v1, off);
        float tc = __shfl_up(c, off);
        if (lane >= off && gg == g) { v0 += t0; v1 += t1; c += tc; }
    }
    int gn = __shfl_down(g, 1);
    if (g >= 0 && (lane == 63 || gn != g)) {
        atomicAdd(&sums[g * EMB + 0], v0);
        atomicAdd(&sums[g * EMB + 1], v1);
        atomicAdd(&cntf[g], c);
    }
}

__global__ void final_kernel(const float* __restrict__ sums, const float* __restrict__ cntf,
                             float* __restrict__ out, int G) {
    int g = blockIdx.x * blockDim.x + threadIdx.x;
    if (g >= G) return;
    float c = fmaxf(cntf[g], 1.0f);
    out[g * EMB + 0] = sums[g * EMB + 0] / c;
    out[g * EMB + 1] = sums[g * EMB + 1] / c;
}

// ---------------------------------------------------------------------------
extern "C" void kernel_launch(void* const* d_in, const int* in_sizes, int n_in,
                              void* d_out, int out_size, void* d_ws, size_t ws_size,
                              hipStream_t stream) {
    const float* x     = (const float*)d_in[0];
    const int*   ei    = (const int*)d_in[1];
    const int*   batch = (const int*)d_in[2];
    const float* W1    = (const float*)d_in[3];
    const float* b1    = (const float*)d_in[4];
    const float* W2    = (const float*)d_in[5];
    const float* b2    = (const float*)d_in[6];
    float* out = (float*)d_out;

    const int N = in_sizes[0] / FIN;   // 100000
    const int E = in_sizes[1] / 2;     // 1600000
    const int G = out_size / EMB;      // 512
    const int* src = ei;
    const int* dst = ei + E;
    const int NB = (N + 255) / 256;

    // ---- workspace layout (16 B aligned chunks) ----
    char* p = (char*)d_ws;
    auto take = [&](size_t bytes) { char* r = p; p += (bytes + 15) & ~(size_t)15; return r; };
    int*   cnt_i  = (int*)take(sizeof(int) * N);
    int*   cursor = (int*)take(sizeof(int) * N);
    int*   rowptr = (int*)take(sizeof(int) * (N + 1));
    int*   bsums  = (int*)take(sizeof(int) * 512);
    int2*  csr    = (int2*)take(sizeof(int2) * E);
    unsigned short* h1b = (unsigned short*)take(sizeof(unsigned short) * (size_t)N * HID);
    float* dinv   = (float*)take(sizeof(float) * N);
    float* h2     = (float*)take(sizeof(float) * (size_t)N * EMB);
    float* sums   = (float*)take(sizeof(float) * G * EMB);
    float* cntf   = (float*)take(sizeof(float) * G);

    // 1. zero cnt, sums+cntf (contiguous)
    zero_i_kernel<<<(N + 255) / 256, 256, 0, stream>>>(cnt_i, N);
    zero_i_kernel<<<(3 * G + 255) / 256, 256, 0, stream>>>((int*)sums, 3L * G);
    // 2. degree histogram
    degree_kernel<<<(E + 255) / 256, 256, 0, stream>>>(dst, cnt_i, E);
    // 3. scan -> rowptr
    scan1_kernel<<<NB, 256, 0, stream>>>(cnt_i, rowptr, bsums, N);
    scan2_kernel<<<1, 512, 0, stream>>>(bsums, NB);
    scan3_kernel<<<NB, 256, 0, stream>>>(rowptr, bsums, N);
    // 4. dinv + cursor seed, then packed CSR fill
    dinv_cursor_kernel<<<(N + 255) / 256, 256, 0, stream>>>(cnt_i, rowptr, dinv, cursor, N);
    fill_csr_kernel<<<(E + 255) / 256, 256, 0, stream>>>(src, dst, cursor, dinv, csr, E);
    // 5. h1 = x @ W1 (MFMA, bf16 out)
    gemm1_kernel<<<(N + 63) / 64, 256, 0, stream>>>(x, W1, h1b, N);
    // 6. fused agg1 + relu + W2 (4 nodes/wave)
    agg1_layer2_kernel<<<(int)(((long)N * 16 + 255) / 256), 256, 0, stream>>>(
        rowptr, csr, h1b, dinv, b1, W2, h2, N);
    // 7. fused agg2 + pool
    agg2_pool_kernel<<<(N + 255) / 256, 256, 0, stream>>>(
        rowptr, csr, h2, dinv, b2, batch, sums, cntf, N);
    final_kernel<<<(G + 255) / 256, 256, 0, stream>>>(sums, cntf, out, G);
}

// Round 5
// 303.967 us; speedup vs baseline: 3.3437x; 1.3024x over previous
//
#include <hip/hip_runtime.h>
#include <hip/hip_bf16.h>

#define FIN 256
#define HID 64
#define EMB 2
#define BKB 9            // bucket = dst >> 9 (512 nodes per bucket)
#define BKSZ 512
#define MAXBK 256        // supports N <= 131072
#define NBLK 256         // blocks for binning passes

typedef __bf16 bf16x8 __attribute__((ext_vector_type(8)));
typedef float  f32x16 __attribute__((ext_vector_type(16)));

// ---- bf16 helpers (RNE) ----
static __device__ __forceinline__ unsigned short f2bf(float f) {
    union { float f; unsigned int u; } v; v.f = f;
    unsigned int u = v.u;
    unsigned int r = (u + 0x7fffu + ((u >> 16) & 1u)) >> 16;
    return (unsigned short)r;
}
static __device__ __forceinline__ float bf2f(unsigned short h) {
    union { unsigned int u; float f; } v; v.u = ((unsigned int)h) << 16;
    return v.f;
}

// ---------------------------------------------------------------------------
__global__ void zero_i_kernel(int* __restrict__ p, long n) {
    long i = (long)blockIdx.x * blockDim.x + threadIdx.x;
    if (i < n) p[i] = 0;
}

// 3-kernel exclusive scan: offs[0]=0, offs[i+1]=inclusive(cnt[0..i])
__global__ void scan1_kernel(const int* __restrict__ cnt, int* __restrict__ offs,
                             int* __restrict__ bsums, int M) {
    __shared__ int s[256];
    int tid = threadIdx.x;
    int i = blockIdx.x * 256 + tid;
    int v = (i < M) ? cnt[i] : 0;
    s[tid] = v;
    __syncthreads();
    for (int off = 1; off < 256; off <<= 1) {
        int t = (tid >= off) ? s[tid - off] : 0;
        __syncthreads();
        s[tid] += t;
        __syncthreads();
    }
    if (i < M) offs[i + 1] = s[tid];
    if (tid == 255) bsums[blockIdx.x] = s[255];
    if (i == 0) offs[0] = 0;
}

__global__ void scan2_kernel(int* __restrict__ bsums, int NB) {
    __shared__ int s[512];
    int tid = threadIdx.x;
    s[tid] = (tid < NB) ? bsums[tid] : 0;
    __syncthreads();
    for (int off = 1; off < 512; off <<= 1) {
        int t = (tid >= off) ? s[tid - off] : 0;
        __syncthreads();
        s[tid] += t;
        __syncthreads();
    }
    if (tid < NB) bsums[tid] = s[tid];
}

__global__ void scan3_kernel(int* __restrict__ offs, const int* __restrict__ bsums, int M) {
    int i = blockIdx.x * 256 + threadIdx.x;
    if (i < M && blockIdx.x > 0) offs[i + 1] += bsums[blockIdx.x - 1];
}

// ---------------------------------------------------------------------------
// Pass A1: per-block histogram of coarse buckets (dst>>9) -> counts[bucket][block]
__global__ __launch_bounds__(256) void bin_hist_kernel(
        const int* __restrict__ dst, int* __restrict__ counts, int E, int chunk, int NBK) {
    __shared__ int hist[MAXBK];
    int tid = threadIdx.x;
    for (int b = tid; b < NBK; b += 256) hist[b] = 0;
    __syncthreads();
    int e0 = blockIdx.x * chunk, e1 = min(e0 + chunk, E);
    for (int i = e0 + tid; i < e1; i += 256) atomicAdd(&hist[dst[i] >> BKB], 1);
    __syncthreads();
    for (int b = tid; b < NBK; b += 256) counts[b * gridDim.x + blockIdx.x] = hist[b];
}

// Pass A2: scatter packed (src<<9 | dst&511) into per-(bucket,block) contiguous runs
__global__ __launch_bounds__(256) void bin_scatter_kernel(
        const int* __restrict__ src, const int* __restrict__ dst,
        const int* __restrict__ offs, unsigned* __restrict__ ebuf,
        int E, int chunk, int NBK) {
    __shared__ int cur[MAXBK];
    int tid = threadIdx.x;
    for (int b = tid; b < NBK; b += 256) cur[b] = offs[b * gridDim.x + blockIdx.x];
    __syncthreads();
    int e0 = blockIdx.x * chunk, e1 = min(e0 + chunk, E);
    for (int i = e0 + tid; i < e1; i += 256) {
        int s = src[i], d = dst[i];
        int b = d >> BKB;
        int pos = atomicAdd(&cur[b], 1);
        ebuf[pos] = ((unsigned)s << BKB) | (unsigned)(d & (BKSZ - 1));
    }
}

// Pass B: one block per bucket. In-LDS node histogram -> degree/dinv/rowptr,
// then scatter src indices within the bucket's contiguous region (line-local).
__global__ __launch_bounds__(256) void build_kernel(
        const unsigned* __restrict__ ebuf, const int* __restrict__ offs,
        int* __restrict__ rowptr, float* __restrict__ dinv, int* __restrict__ csr,
        int N, int E) {
    __shared__ int hist[BKSZ];
    __shared__ int scanb[256];
    __shared__ int cur[BKSZ];
    const int b = blockIdx.x, tid = threadIdx.x;
    const int r0 = offs[b * NBLK];
    const int r1 = offs[(b + 1) * NBLK];   // last bucket: offs[M] = E
    const int nb0 = b * BKSZ;

    hist[tid] = 0; hist[tid + 256] = 0;
    __syncthreads();
    for (int i = r0 + tid; i < r1; i += 256)
        atomicAdd(&hist[ebuf[i] & (BKSZ - 1u)], 1);
    __syncthreads();

    int h0 = hist[2 * tid], h1 = hist[2 * tid + 1];
    if (nb0 + 2 * tid < N)     dinv[nb0 + 2 * tid]     = rsqrtf((float)h0 + 1.f);
    if (nb0 + 2 * tid + 1 < N) dinv[nb0 + 2 * tid + 1] = rsqrtf((float)h1 + 1.f);
    scanb[tid] = h0 + h1;
    __syncthreads();
    for (int off = 1; off < 256; off <<= 1) {
        int t = (tid >= off) ? scanb[tid - off] : 0;
        __syncthreads();
        scanb[tid] += t;
        __syncthreads();
    }
    int base0 = scanb[tid] - (h0 + h1);    // exclusive offset of local node 2*tid
    int o0 = base0, o1 = base0 + h0;
    cur[2 * tid] = o0; cur[2 * tid + 1] = o1;
    if (nb0 + 2 * tid < N)     rowptr[nb0 + 2 * tid]     = r0 + o0;
    if (nb0 + 2 * tid + 1 < N) rowptr[nb0 + 2 * tid + 1] = r0 + o1;
    if (nb0 + BKSZ >= N && tid == 0) rowptr[N] = E;
    __syncthreads();
    for (int i = r0 + tid; i < r1; i += 256) {
        unsigned u = ebuf[i];
        int loc = (int)(u & (BKSZ - 1u));
        int p = atomicAdd(&cur[loc], 1);
        csr[r0 + p] = (int)(u >> BKB);
    }
}

// ---------------------------------------------------------------------------
// h1' = dinv * (x @ W1) via MFMA (bf16 hi/lo split), bf16 store.
__global__ __launch_bounds__(256) void gemm1_kernel(
        const float* __restrict__ x, const float* __restrict__ W,
        const float* __restrict__ dinv, unsigned short* __restrict__ h1b, int N) {
    __shared__ __align__(16) __bf16 A_hi[2 * 4 * 64 * 8];
    __shared__ __align__(16) __bf16 A_lo[2 * 4 * 64 * 8];
    __shared__ __align__(16) __bf16 B_hi[2 * 4 * 64 * 8];
    __shared__ __align__(16) __bf16 B_lo[2 * 4 * 64 * 8];

    const int tid = threadIdx.x;
    const int base = blockIdx.x * 64;
    const int w = tid >> 6;
    const int l = tid & 63;
    const int mg = w >> 1, ng = w & 1;

    f32x16 acc = {};

    const int r  = tid & 63;
    const int ks = tid >> 6;
    const int rl = r & 31, rh = r >> 5;

    for (int ch = 0; ch < 4; ++ch) {
        const int ck0 = ch * 64;
        __syncthreads();
        {
            int row = base + r;
            float f[16];
            if (row < N) {
                const float* xp = &x[(size_t)row * FIN + ck0 + ks * 16];
                float4 v0 = *(const float4*)(xp + 0);
                float4 v1 = *(const float4*)(xp + 4);
                float4 v2 = *(const float4*)(xp + 8);
                float4 v3 = *(const float4*)(xp + 12);
                f[0]=v0.x; f[1]=v0.y; f[2]=v0.z; f[3]=v0.w;
                f[4]=v1.x; f[5]=v1.y; f[6]=v1.z; f[7]=v1.w;
                f[8]=v2.x; f[9]=v2.y; f[10]=v2.z; f[11]=v2.w;
                f[12]=v3.x; f[13]=v3.y; f[14]=v3.z; f[15]=v3.w;
            } else {
                #pragma unroll
                for (int q = 0; q < 16; ++q) f[q] = 0.f;
            }
            bf16x8 ha, hb, la, lb;
            #pragma unroll
            for (int q = 0; q < 8; ++q) {
                __bf16 h0 = (__bf16)f[q];
                ha[q] = h0; la[q] = (__bf16)(f[q] - (float)h0);
                __bf16 h1v = (__bf16)f[q + 8];
                hb[q] = h1v; lb[q] = (__bf16)(f[q + 8] - (float)h1v);
            }
            int ra = ((rh * 4 + ks) * 64 + rl) * 8;
            int rb = ((rh * 4 + ks) * 64 + 32 + rl) * 8;
            *(bf16x8*)&A_hi[ra] = ha; *(bf16x8*)&A_hi[rb] = hb;
            *(bf16x8*)&A_lo[ra] = la; *(bf16x8*)&A_lo[rb] = lb;
        }
        {
            const float* wp = &W[(size_t)(ck0 + ks * 16) * HID + r];
            float f[16];
            #pragma unroll
            for (int q = 0; q < 16; ++q) f[q] = wp[q * HID];
            bf16x8 ha, hb, la, lb;
            #pragma unroll
            for (int q = 0; q < 8; ++q) {
                __bf16 h0 = (__bf16)f[q];
                ha[q] = h0; la[q] = (__bf16)(f[q] - (float)h0);
                __bf16 h1v = (__bf16)f[q + 8];
                hb[q] = h1v; lb[q] = (__bf16)(f[q + 8] - (float)h1v);
            }
            int ra = ((rh * 4 + ks) * 64 + rl) * 8;
            int rb = ((rh * 4 + ks) * 64 + 32 + rl) * 8;
            *(bf16x8*)&B_hi[ra] = ha; *(bf16x8*)&B_hi[rb] = hb;
            *(bf16x8*)&B_lo[ra] = la; *(bf16x8*)&B_lo[rb] = lb;
        }
        __syncthreads();

        #pragma unroll
        for (int s = 0; s < 4; ++s) {
            bf16x8 a_h = *(const bf16x8*)&A_hi[((mg * 4 + s) * 64 + l) * 8];
            bf16x8 a_l = *(const bf16x8*)&A_lo[((mg * 4 + s) * 64 + l) * 8];
            bf16x8 b_h = *(const bf16x8*)&B_hi[((ng * 4 + s) * 64 + l) * 8];
            bf16x8 b_l = *(const bf16x8*)&B_lo[((ng * 4 + s) * 64 + l) * 8];
            acc = __builtin_amdgcn_mfma_f32_32x32x16_bf16(a_h, b_h, acc, 0, 0, 0);
            acc = __builtin_amdgcn_mfma_f32_32x32x16_bf16(a_h, b_l, acc, 0, 0, 0);
            acc = __builtin_amdgcn_mfma_f32_32x32x16_bf16(a_l, b_h, acc, 0, 0, 0);
        }
    }

    const int col = l & 31;
    const int rbase = 4 * (l >> 5);
    #pragma unroll
    for (int reg = 0; reg < 16; ++reg) {
        int row = (reg & 3) + 8 * (reg >> 2) + rbase;
        int node = base + mg * 32 + row;
        if (node < N)
            h1b[(size_t)node * HID + ng * 32 + col] = f2bf(acc[reg] * dinv[node]);
    }
}

// ---------------------------------------------------------------------------
// Fused layer-1 CSR gather (pure sum of pre-scaled h1') + b1 + ReLU + (64->2).
// 4 nodes per wave: 16 lanes/node, lane = 4 feats (ushort4 gather).
__global__ __launch_bounds__(256) void agg1_layer2_kernel(
        const int* __restrict__ rowptr, const int* __restrict__ csr,
        const unsigned short* __restrict__ h1b,
        const float* __restrict__ dinv, const float* __restrict__ b1,
        const float* __restrict__ W2, float* __restrict__ h2, int N) {
    long t = (long)blockIdx.x * blockDim.x + threadIdx.x;
    int n = (int)(t >> 4);
    int li = threadIdx.x & 15;
    if (n >= N) return;
    const ushort4* h14 = (const ushort4*)h1b;

    float di = dinv[n];
    ushort4 sl = h14[(size_t)n * 16 + li];       // self term (h1' already scaled)
    float v0 = bf2f(sl.x), v1 = bf2f(sl.y);
    float v2 = bf2f(sl.z), v3 = bf2f(sl.w);

    int j0 = rowptr[n], j1 = rowptr[n + 1];
    int j = j0;
    for (; j + 3 < j1; j += 4) {
        int s0 = csr[j], s1 = csr[j + 1], s2 = csr[j + 2], s3 = csr[j + 3];
        ushort4 g0 = h14[(size_t)s0 * 16 + li];
        ushort4 g1 = h14[(size_t)s1 * 16 + li];
        ushort4 g2 = h14[(size_t)s2 * 16 + li];
        ushort4 g3 = h14[(size_t)s3 * 16 + li];
        v0 += bf2f(g0.x) + bf2f(g1.x) + bf2f(g2.x) + bf2f(g3.x);
        v1 += bf2f(g0.y) + bf2f(g1.y) + bf2f(g2.y) + bf2f(g3.y);
        v2 += bf2f(g0.z) + bf2f(g1.z) + bf2f(g2.z) + bf2f(g3.z);
        v3 += bf2f(g0.w) + bf2f(g1.w) + bf2f(g2.w) + bf2f(g3.w);
    }
    for (; j < j1; ++j) {
        int s = csr[j];
        ushort4 g = h14[(size_t)s * 16 + li];
        v0 += bf2f(g.x); v1 += bf2f(g.y); v2 += bf2f(g.z); v3 += bf2f(g.w);
    }

    const float4 b4 = *(const float4*)&b1[li * 4];
    v0 = fmaxf(di * v0 + b4.x, 0.f); v1 = fmaxf(di * v1 + b4.y, 0.f);
    v2 = fmaxf(di * v2 + b4.z, 0.f); v3 = fmaxf(di * v3 + b4.w, 0.f);

    const float4* W24 = (const float4*)W2;
    float4 wa = W24[li * 2], wb = W24[li * 2 + 1];
    float r0 = v0 * wa.x + v1 * wa.z + v2 * wb.x + v3 * wb.z;
    float r1 = v0 * wa.y + v1 * wa.w + v2 * wb.y + v3 * wb.w;
    #pragma unroll
    for (int off = 1; off < 16; off <<= 1) {
        r0 += __shfl_xor(r0, off);
        r1 += __shfl_xor(r1, off);
    }
    if (li == 0) *(float2*)&h2[(size_t)n * EMB] = make_float2(r0 * di, r1 * di);  // h2' = dinv*h2
}

// ---------------------------------------------------------------------------
// Fused layer-2 CSR gather (pure sum of h2') + b2 + global mean pool.
__global__ __launch_bounds__(256) void agg2_pool_kernel(
        const int* __restrict__ rowptr, const int* __restrict__ csr,
        const float* __restrict__ h2,
        const float* __restrict__ dinv, const float* __restrict__ b2,
        const int* __restrict__ batch,
        float* __restrict__ sums, float* __restrict__ cntf, int N) {
    int n = blockIdx.x * blockDim.x + threadIdx.x;
    int lane = threadIdx.x & 63;
    const float2* h2v = (const float2*)h2;
    float v0 = 0.f, v1 = 0.f, c = 0.f;
    int g = -1;
    if (n < N) {
        float di = dinv[n];
        float2 hs = h2v[n];
        v0 = hs.x; v1 = hs.y;                    // self (h2' pre-scaled)
        int j0 = rowptr[n], j1 = rowptr[n + 1];
        int j = j0;
        for (; j + 3 < j1; j += 4) {
            int s0 = csr[j], s1 = csr[j + 1], s2 = csr[j + 2], s3 = csr[j + 3];
            float2 a = h2v[s0], b = h2v[s1], cc = h2v[s2], d = h2v[s3];
            v0 += a.x + b.x + cc.x + d.x;
            v1 += a.y + b.y + cc.y + d.y;
        }
        for (; j < j1; ++j) {
            float2 hv = h2v[csr[j]];
            v0 += hv.x; v1 += hv.y;
        }
        v0 = di * v0 + b2[0];
        v1 = di * v1 + b2[1];
        g = batch[n];
        c = 1.f;
    }
    #pragma unroll
    for (int off = 1; off < 64; off <<= 1) {
        int gg = __shfl_up(g, off);
        float t0 = __shfl_up(v0, off);
        float t1 = __shfl_up(v1, off);
        float tc = __shfl_up(c, off);
        if (lane >= off && gg == g) { v0 += t0; v1 += t1; c += tc; }
    }
    int gn = __shfl_down(g, 1);
    if (g >= 0 && (lane == 63 || gn != g)) {
        atomicAdd(&sums[g * EMB + 0], v0);
        atomicAdd(&sums[g * EMB + 1], v1);
        atomicAdd(&cntf[g], c);
    }
}

__global__ void final_kernel(const float* __restrict__ sums, const float* __restrict__ cntf,
                             float* __restrict__ out, int G) {
    int g = blockIdx.x * blockDim.x + threadIdx.x;
    if (g >= G) return;
    float c = fmaxf(cntf[g], 1.0f);
    out[g * EMB + 0] = sums[g * EMB + 0] / c;
    out[g * EMB + 1] = sums[g * EMB + 1] / c;
}

// ---------------------------------------------------------------------------
extern "C" void kernel_launch(void* const* d_in, const int* in_sizes, int n_in,
                              void* d_out, int out_size, void* d_ws, size_t ws_size,
                              hipStream_t stream) {
    const float* x     = (const float*)d_in[0];
    const int*   ei    = (const int*)d_in[1];
    const int*   batch = (const int*)d_in[2];
    const float* W1    = (const float*)d_in[3];
    const float* b1    = (const float*)d_in[4];
    const float* W2    = (const float*)d_in[5];
    const float* b2    = (const float*)d_in[6];
    float* out = (float*)d_out;

    const int N = in_sizes[0] / FIN;   // 100000
    const int E = in_sizes[1] / 2;     // 1600000
    const int G = out_size / EMB;      // 512
    const int* src = ei;
    const int* dst = ei + E;

    const int NBK = (N + BKSZ - 1) / BKSZ;   // 196 coarse buckets
    const int M = NBK * NBLK;                // count-matrix size (50176)
    const int NBs = (M + 255) / 256;         // scan blocks (196)
    const int chunk = (E + NBLK - 1) / NBLK; // 6250 edges per bin block

    // ---- workspace layout (16 B aligned chunks) ----
    char* p = (char*)d_ws;
    auto take = [&](size_t bytes) { char* r = p; p += (bytes + 15) & ~(size_t)15; return r; };
    int*      counts = (int*)take(sizeof(int) * M);
    int*      offs   = (int*)take(sizeof(int) * (M + 1));
    int*      bsums  = (int*)take(sizeof(int) * 512);
    unsigned* ebuf   = (unsigned*)take(sizeof(unsigned) * E);
    int*      csr    = (int*)take(sizeof(int) * E);
    int*      rowptr = (int*)take(sizeof(int) * (N + 1));
    float*    dinv   = (float*)take(sizeof(float) * N);
    unsigned short* h1b = (unsigned short*)take(sizeof(unsigned short) * (size_t)N * HID);
    float*    h2     = (float*)take(sizeof(float) * (size_t)N * EMB);
    float*    sums   = (float*)take(sizeof(float) * G * EMB);
    float*    cntf   = (float*)take(sizeof(float) * G);

    // 1. zero pool accumulators
    zero_i_kernel<<<(3 * G + 255) / 256, 256, 0, stream>>>((int*)sums, 3L * G);
    // 2. CSR build: coarse hist -> scan -> coarse scatter -> fine build
    bin_hist_kernel<<<NBLK, 256, 0, stream>>>(dst, counts, E, chunk, NBK);
    scan1_kernel<<<NBs, 256, 0, stream>>>(counts, offs, bsums, M);
    scan2_kernel<<<1, 512, 0, stream>>>(bsums, NBs);
    scan3_kernel<<<NBs, 256, 0, stream>>>(offs, bsums, M);
    bin_scatter_kernel<<<NBLK, 256, 0, stream>>>(src, dst, offs, ebuf, E, chunk, NBK);
    build_kernel<<<NBK, 256, 0, stream>>>(ebuf, offs, rowptr, dinv, csr, N, E);
    // 3. h1' = dinv * (x @ W1)  (MFMA, bf16 out)
    gemm1_kernel<<<(N + 63) / 64, 256, 0, stream>>>(x, W1, dinv, h1b, N);
    // 4. fused agg1 + relu + W2 -> h2' = dinv * h2
    agg1_layer2_kernel<<<(int)(((long)N * 16 + 255) / 256), 256, 0, stream>>>(
        rowptr, csr, h1b, dinv, b1, W2, h2, N);
    // 5. fused agg2 + pool
    agg2_pool_kernel<<<(N + 255) / 256, 256, 0, stream>>>(
        rowptr, csr, h2, dinv, b2, batch, sums, cntf, N);
    final_kernel<<<(G + 255) / 256, 256, 0, stream>>>(sums, cntf, out, G);
}